// Round 14
// baseline (2106.481 us; speedup 1.0000x reference)
//
#include <hip/hip_runtime.h>
#include <math.h>

#define SEQ 128
#define BATCH 32
#define EDIM 300
#define HDIM 200
#define G4 800      // 4*H
#define NGATE 1600  // 2 dirs * 4 * H
#define KC 25       // 25 chunks of 8 halves = 200 k-values
#define NLDS 11     // chunks held in LDS (140.8 KB dynamic)
#define CHSTRIDE 6400   // halves between k-chunks in Upk: 800 rows * 8

#define K0PAD 320   // layer-0 GEMM K (300 padded)
#define K1PAD 416   // layer-1 GEMM K (400 padded)

#define TLSTM 256   // k_lstm block: 4 waves, 200 workers x 4 gate rows

typedef _Float16 h2t __attribute__((ext_vector_type(2)));
typedef _Float16 f16x8 __attribute__((ext_vector_type(8)));
typedef float f32x4 __attribute__((ext_vector_type(4)));

__device__ __forceinline__ h2t u2h(unsigned v) {
    union { unsigned u; h2t h; } c; c.u = v; return c.h;
}

// v_dot2_f32_f16: acc += a.x*b.x + a.y*b.y  (f32 accumulate)
__device__ __forceinline__ float dot2acc(h2t a, h2t b, float c) {
    return __builtin_amdgcn_fdot2(a, b, c, false);
}

// 8 halves x 8 halves -> acc (4 dot2)
__device__ __forceinline__ float dot8(uint4 u, uint4 h, float acc) {
    acc = dot2acc(u2h(u.x), u2h(h.x), acc);
    acc = dot2acc(u2h(u.y), u2h(h.y), acc);
    acc = dot2acc(u2h(u.z), u2h(h.z), acc);
    acc = dot2acc(u2h(u.w), u2h(h.w), acc);
    return acc;
}

__device__ __forceinline__ float fast_sigmoid(float x) {
    return 1.f / (1.f + __expf(-x));
}
__device__ __forceinline__ float fast_tanh(float x) {
    x = fminf(fmaxf(x, -15.f), 15.f);
    float e = __expf(2.f * x);
    return (e - 1.f) / (e + 1.f);
}

// ------------------------------------------------------------------
// K1: embedding gather -> f16, K zero-padded to K0PAD
// ------------------------------------------------------------------
__global__ void k_gather(const int* __restrict__ words,
                         const float* __restrict__ emb,
                         _Float16* __restrict__ X0h)
{
    int row = blockIdx.x;          // row = t*32 + b
    int t = row >> 5;
    int b = row & 31;
    int w = words[b * SEQ + t];
    const float* src = emb + (size_t)w * EDIM;
    _Float16* dst = X0h + (size_t)row * K0PAD;
    for (int e = threadIdx.x; e < K0PAD; e += blockDim.x)
        dst[e] = (e < EDIM) ? (_Float16)src[e] : (_Float16)0.f;
}

// ------------------------------------------------------------------
// K1c: cast W (N,K) f32 -> (N,Kpad) f16, zero-padded
// ------------------------------------------------------------------
__global__ void k_castW(const float* __restrict__ W,
                        _Float16* __restrict__ Wh,
                        int N, int K, int Kpad)
{
    int idx = blockIdx.x * blockDim.x + threadIdx.x;
    if (idx >= N * Kpad) return;
    int n = idx / Kpad, k = idx % Kpad;
    Wh[idx] = (k < K) ? (_Float16)W[(size_t)n * K + k] : (_Float16)0.f;
}

// ------------------------------------------------------------------
// K1b: pack Whh (2,800,200) f32 -> Upk fp16, chunk-major coalesced
// ------------------------------------------------------------------
__global__ void k_pack(const float* __restrict__ Whh,
                       _Float16* __restrict__ Upk)
{
    int idx = blockIdx.x * blockDim.x + threadIdx.x;   // (d*KC+kc)*800 + r
    if (idx >= 2 * KC * 800) return;
    int r  = idx % 800;
    int kc = (idx / 800) % KC;
    int d  = idx / (800 * KC);
    const float* src = Whh + ((size_t)d * G4 + r) * HDIM + kc * 8;
    _Float16* dst = Upk + (size_t)idx * 8;
#pragma unroll
    for (int j = 0; j < 8; ++j) dst[j] = (_Float16)src[j];
}

// ------------------------------------------------------------------
// K2/K4: MFMA f16 GEMM:  C[M,N] = A[M,Kpad] @ Bw[N,Kpad]^T + bias[N]
// (unchanged from R13 -- verified, ~15-30 us each)
// ------------------------------------------------------------------
#define GBM 64
#define GBN 64
#define GBK 32
#define GLD 40

__global__ __launch_bounds__(256)
void k_gemm_mfma(const _Float16* __restrict__ A,
                 const _Float16* __restrict__ Bw,
                 const float* __restrict__ bias,
                 float* __restrict__ C,
                 int M, int N, int Kpad)
{
    __shared__ __align__(16) _Float16 As[GBM][GLD];
    __shared__ __align__(16) _Float16 Bs[GBN][GLD];
    int tid = threadIdx.x;
    int wave = tid >> 6;
    int lane = tid & 63;
    int bm = blockIdx.y * GBM, bn = blockIdx.x * GBN;

    int srow = tid >> 2;          // staging: row 0..63
    int sseg = (tid & 3) * 8;     // k-segment 0,8,16,24

    f32x4 acc0 = {0,0,0,0}, acc1 = {0,0,0,0}, acc2 = {0,0,0,0}, acc3 = {0,0,0,0};
    int am = lane & 15;
    int kg = (lane >> 4) * 8;

    for (int k0 = 0; k0 < Kpad; k0 += GBK) {
        *(f16x8*)&As[srow][sseg] = *(const f16x8*)&A[(size_t)(bm + srow) * Kpad + k0 + sseg];
        *(f16x8*)&Bs[srow][sseg] = *(const f16x8*)&Bw[(size_t)(bn + srow) * Kpad + k0 + sseg];
        __syncthreads();
        f16x8 af = *(const f16x8*)&As[wave * 16 + am][kg];
        f16x8 b0 = *(const f16x8*)&Bs[ 0 + am][kg];
        f16x8 b1 = *(const f16x8*)&Bs[16 + am][kg];
        f16x8 b2 = *(const f16x8*)&Bs[32 + am][kg];
        f16x8 b3 = *(const f16x8*)&Bs[48 + am][kg];
        acc0 = __builtin_amdgcn_mfma_f32_16x16x32_f16(af, b0, acc0, 0, 0, 0);
        acc1 = __builtin_amdgcn_mfma_f32_16x16x32_f16(af, b1, acc1, 0, 0, 0);
        acc2 = __builtin_amdgcn_mfma_f32_16x16x32_f16(af, b2, acc2, 0, 0, 0);
        acc3 = __builtin_amdgcn_mfma_f32_16x16x32_f16(af, b3, acc3, 0, 0, 0);
        __syncthreads();
    }
    int col0 = lane & 15;
    int row0 = (lane >> 4) * 4;
#pragma unroll
    for (int r2 = 0; r2 < 4; ++r2) {
        int m = bm + wave * 16 + row0 + r2;
        float* crow = &C[(size_t)m * N + bn];
        crow[ 0 + col0] = acc0[r2] + bias[bn +  0 + col0];
        crow[16 + col0] = acc1[r2] + bias[bn + 16 + col0];
        crow[32 + col0] = acc2[r2] + bias[bn + 32 + col0];
        crow[48 + col0] = acc3[r2] + bias[bn + 48 + col0];
    }
}

// ------------------------------------------------------------------
// K3/K5: recurrent BiLSTM layer -- LDS-read-minimized shape.
// R13 lesson: bottleneck = LDS pipe issue (reads x 12 cyc); R6's 3920
// cyc/step == 325 h-broadcasts. Fix: 4 gate rows PER THREAD:
//  - 256 threads (200 workers): h-broadcasts 25 x 4 waves = 100/step
//  - U: 11 chunks in LDS (137 reads/step min) + 14 streamed from L2
//    (179 KB/step, step-invariant -> prefetchable, VMEM pipe overlaps)
//  - all 4 gates in-thread -> inline activation, no g_lds, ONE barrier
// LDS pipe ~2850 cyc, VMEM ~2560, VALU ~625 -> step ~3000 cyc.
// launch_bounds(256,1): 1 wave/SIMD, 512-reg budget -> no spill
// pressure; compiler MAY hoist U-LDS reads to regs (strictly better).
// ------------------------------------------------------------------
__global__ __launch_bounds__(TLSTM, 1)
void k_lstm(const float* __restrict__ Xg,
            const _Float16* __restrict__ Upk,  // (2, KC, 800, 8) halves
            float* __restrict__ Hout,          // (S, B, 400) f32
            _Float16* __restrict__ Houth)      // (S*B, 416) f16
{
    int blk = blockIdx.x;      // 0..63
    int d = blk >> 5;          // direction
    int b = blk & 31;          // batch
    int w = threadIdx.x;
    bool worker = (w < HDIM);
    int ww = worker ? w : (HDIM - 1);   // clamped unit index

    extern __shared__ __align__(16) char smem[];
    _Float16 (*lds_u)[800][8] = (_Float16 (*)[800][8])smem;        // 140800 B
    _Float16 (*hbuf)[HDIM] = (_Float16 (*)[HDIM])(smem + 140800);  // 800 B

    // stage chunks 0..NLDS-1 into LDS (coalesced global reads)
    for (int idx = w; idx < NLDS * 800; idx += TLSTM) {
        int kc = idx / 800, r = idx % 800;
        *(uint4*)&lds_u[kc][r][0] =
            *(const uint4*)(Upk + ((size_t)(d * KC + kc) * 800 + r) * 8);
    }

    if (worker) hbuf[0][w] = (_Float16)0.f;
    float c = 0.f;

    // per-thread Xg gate addresses (unit ww: gates at +0,+200,+400,+600)
    const float* xg_ptr = Xg + (size_t)b * NGATE + (size_t)d * G4 + ww;
    const ptrdiff_t sstride = (ptrdiff_t)BATCH * NGATE;

    // streamed-chunk row bases (16B per row within chunk kc)
    const _Float16* upg = Upk + (size_t)d * KC * CHSTRIDE;

    __syncthreads();

    int tt0 = d ? (SEQ - 1) : 0;
    float xI_c = 0.f, xF_c = 0.f, xG_c = 0.f, xO_c = 0.f;
    if (worker) {
        const float* p = xg_ptr + (ptrdiff_t)tt0 * sstride;
        xI_c = p[0]; xF_c = p[HDIM]; xG_c = p[2*HDIM]; xO_c = p[3*HDIM];
    }

    const _Float16* hcur = hbuf[0];
    _Float16* hnxt = hbuf[1];

#pragma unroll 1
    for (int t = 0; t < SEQ; ++t) {
        int tt = d ? (SEQ - 1 - t) : t;
        // prefetch next step's 4 Xg gate values
        float xI_n = 0.f, xF_n = 0.f, xG_n = 0.f, xO_n = 0.f;
        if (worker && t + 1 < SEQ) {
            const float* p = xg_ptr + (ptrdiff_t)(d ? (SEQ-2-t) : (t+1)) * sstride;
            xI_n = p[0]; xF_n = p[HDIM]; xG_n = p[2*HDIM]; xO_n = p[3*HDIM];
        }

        float aI = xI_c, aF = xF_c, aG = xG_c, aO = xO_c;
        // LDS-resident chunks: 1 h-broadcast + 4 own-row reads per chunk
#pragma unroll
        for (int kc = 0; kc < NLDS; ++kc) {
            uint4 hv = *(const uint4*)&hcur[8 * kc];
            uint4 uI = *(const uint4*)&lds_u[kc][ww          ][0];
            uint4 uF = *(const uint4*)&lds_u[kc][ww + HDIM   ][0];
            uint4 uG = *(const uint4*)&lds_u[kc][ww + 2*HDIM ][0];
            uint4 uO = *(const uint4*)&lds_u[kc][ww + 3*HDIM ][0];
            aI = dot8(uI, hv, aI);
            aF = dot8(uF, hv, aF);
            aG = dot8(uG, hv, aG);
            aO = dot8(uO, hv, aO);
        }
        // streamed chunks from L2 (addresses step-invariant, coalesced)
#pragma unroll
        for (int kc = NLDS; kc < KC; ++kc) {
            uint4 hv = *(const uint4*)&hcur[8 * kc];
            const _Float16* base = upg + (size_t)kc * CHSTRIDE;
            uint4 uI = *(const uint4*)(base + (ww          ) * 8);
            uint4 uF = *(const uint4*)(base + (ww + HDIM   ) * 8);
            uint4 uG = *(const uint4*)(base + (ww + 2*HDIM ) * 8);
            uint4 uO = *(const uint4*)(base + (ww + 3*HDIM ) * 8);
            aI = dot8(uI, hv, aI);
            aF = dot8(uF, hv, aF);
            aG = dot8(uG, hv, aG);
            aO = dot8(uO, hv, aO);
        }

        if (worker) {
            float si = fast_sigmoid(aI);
            float sf = fast_sigmoid(aF);
            float so = fast_sigmoid(aO);
            c = sf * c + si * fast_tanh(aG);
            float hh = so * fast_tanh(c);
            hnxt[w] = (_Float16)hh;
            size_t rowi = (size_t)tt * BATCH + b;
            Hout[rowi * (2 * HDIM) + d * HDIM + w] = hh;
            Houth[rowi * K1PAD + d * HDIM + w] = (_Float16)hh;
        } else if (d == 0 && w >= HDIM && w < HDIM + 16) {
            // zero K-pad columns 400..415 (poisoned workspace)
            Houth[((size_t)tt * BATCH + b) * K1PAD + 400 + (w - HDIM)] = (_Float16)0.f;
        }
        __syncthreads();

        const _Float16* tmp = hcur; hcur = hnxt; hnxt = (_Float16*)tmp;
        xI_c = xI_n; xF_c = xF_n; xG_c = xG_n; xO_c = xO_n;
    }
}

// ------------------------------------------------------------------
// K6: out[b][s][o] = sigmoid(H1[s][b][:] . Wo[o][:] + bo[o])
// ------------------------------------------------------------------
__global__ void k_out(const float* __restrict__ H1,
                      const float* __restrict__ Wo,
                      const float* __restrict__ bo,
                      float* __restrict__ out)
{
    int idx = blockIdx.x * blockDim.x + threadIdx.x;
    if (idx >= BATCH * SEQ * 17) return;
    int o = idx % 17;
    int bs = idx / 17;
    int b = bs >> 7;      // /128
    int s = bs & 127;
    const float* hrow = H1 + ((size_t)(s * BATCH + b)) * (2 * HDIM);
    const float* wrow = Wo + (size_t)o * (2 * HDIM);
    float acc = bo[o];
#pragma unroll 4
    for (int j = 0; j < 2 * HDIM; ++j) acc += hrow[j] * wrow[j];
    out[idx] = 1.f / (1.f + __expf(-acc));
}

// ------------------------------------------------------------------
extern "C" void kernel_launch(void* const* d_in, const int* in_sizes, int n_in,
                              void* d_out, int out_size, void* d_ws, size_t ws_size,
                              hipStream_t stream)
{
    const int*   words = (const int*)d_in[0];
    // d_in[1] chars, d_in[2] lens: dead code in the reference
    const float* emb   = (const float*)d_in[3];
    // d_in[4..6]: char conv params, dead
    const float* Wih0  = (const float*)d_in[7];
    const float* Whh0  = (const float*)d_in[8];
    const float* b0    = (const float*)d_in[9];
    const float* Wih1  = (const float*)d_in[10];
    const float* Whh1  = (const float*)d_in[11];
    const float* b1    = (const float*)d_in[12];
    const float* Wo    = (const float*)d_in[13];
    const float* bo    = (const float*)d_in[14];
    float* out = (float*)d_out;

    char* ws = (char*)d_ws;
    const size_t X0H_OFF = 0;                                   // 4096*320*2
    const size_t W0H_OFF = X0H_OFF + (size_t)4096 * K0PAD * 2;
    const size_t W1H_OFF = W0H_OFF + (size_t)NGATE * K0PAD * 2;
    const size_t UP0_OFF = W1H_OFF + (size_t)NGATE * K1PAD * 2;
    const size_t UP1_OFF = UP0_OFF + (size_t)2 * KC * 800 * 8 * 2;
    const size_t XG_OFF  = UP1_OFF + (size_t)2 * KC * 800 * 8 * 2;
    const size_t H1_OFF  = XG_OFF + (size_t)SEQ * BATCH * NGATE * 4;
    const size_t HT0_OFF = H1_OFF + (size_t)SEQ * BATCH * 2 * HDIM * 4;

    _Float16* X0h   = (_Float16*)(ws + X0H_OFF);
    _Float16* W0h   = (_Float16*)(ws + W0H_OFF);
    _Float16* W1h   = (_Float16*)(ws + W1H_OFF);
    _Float16* Upk0  = (_Float16*)(ws + UP0_OFF);
    _Float16* Upk1  = (_Float16*)(ws + UP1_OFF);
    float*    Xg    = (float*)(ws + XG_OFF);
    float*    H1    = (float*)(ws + H1_OFF);
    float*    Hdump = H1;                       // layer-0 f32 out (unused)
    _Float16* Houth0 = (_Float16*)(ws + HT0_OFF);
    _Float16* HouthD = Houth0;                  // layer-1 f16 out (unused)

    // dynamic-LDS cap for k_lstm: 140800 + 800 = 141600 B
    hipFuncSetAttribute((const void*)k_lstm,
                        hipFuncAttributeMaxDynamicSharedMemorySize, 141600);

    // 1. gather embeddings -> X0h f16 (4096, 320)
    k_gather<<<SEQ * BATCH, 128, 0, stream>>>(words, emb, X0h);

    // 1b. weight casts + recurrent packs
    int ncast0 = NGATE * K0PAD, ncast1 = NGATE * K1PAD;
    k_castW<<<(ncast0 + 255) / 256, 256, 0, stream>>>(Wih0, W0h, NGATE, EDIM, K0PAD);
    k_castW<<<(ncast1 + 255) / 256, 256, 0, stream>>>(Wih1, W1h, NGATE, 2 * HDIM, K1PAD);
    int npack = 2 * KC * 800;
    k_pack<<<(npack + 255) / 256, 256, 0, stream>>>(Whh0, Upk0);
    k_pack<<<(npack + 255) / 256, 256, 0, stream>>>(Whh1, Upk1);

    // 2. layer-0 input GEMM (MFMA): Xg = X0h @ W0h^T + b0
    dim3 ggrid(NGATE / GBN, (SEQ * BATCH) / GBM);
    k_gemm_mfma<<<ggrid, 256, 0, stream>>>(X0h, W0h, b0, Xg,
                                           SEQ * BATCH, NGATE, K0PAD);

    // 3. layer-0 recurrence -> Houth0 (f16) [+ f32 dump]
    k_lstm<<<64, TLSTM, 141600, stream>>>(Xg, Upk0, Hdump, Houth0);

    // 4. layer-1 input GEMM (MFMA): Xg = Houth0 @ W1h^T + b1
    k_gemm_mfma<<<ggrid, 256, 0, stream>>>(Houth0, W1h, b1, Xg,
                                           SEQ * BATCH, NGATE, K1PAD);

    // 5. layer-1 recurrence -> H1 (f32) [+ f16 dump]
    k_lstm<<<64, TLSTM, 141600, stream>>>(Xg, Upk1, H1, HouthD);

    // 6. output head
    int nout = BATCH * SEQ * 17;
    k_out<<<(nout + 255) / 256, 256, 0, stream>>>(H1, Wo, bo, out);
}

// Round 15
// 823.589 us; speedup vs baseline: 2.5577x; 2.5577x over previous
//
#include <hip/hip_runtime.h>
#include <math.h>

#define SEQ 128
#define BATCH 32
#define EDIM 300
#define HDIM 200
#define G4 800      // 4*H
#define NGATE 1600  // 2 dirs * 4 * H
#define KC 25       // 25 chunks of 8 halves = 200 k-values
#define NSTREAM 21  // chunks streamed from L2 (R6-optimal split)
#define NLDS 4      // chunks held in LDS (51.2 KB static)
#define CHSTRIDE 6400   // halves between k-chunks in Upk: 800 rows * 8

#define K0PAD 320   // layer-0 GEMM K (300 padded)
#define K1PAD 416   // layer-1 GEMM K (400 padded)

typedef _Float16 h2t __attribute__((ext_vector_type(2)));
typedef _Float16 f16x8 __attribute__((ext_vector_type(8)));
typedef float f32x4 __attribute__((ext_vector_type(4)));

__device__ __forceinline__ h2t u2h(unsigned v) {
    union { unsigned u; h2t h; } c; c.u = v; return c.h;
}

// v_dot2_f32_f16: acc += a.x*b.x + a.y*b.y  (f32 accumulate)
__device__ __forceinline__ float dot2acc(h2t a, h2t b, float c) {
    return __builtin_amdgcn_fdot2(a, b, c, false);
}

// 8 halves x 8 halves -> acc (4 dot2)
__device__ __forceinline__ float dot8(uint4 u, uint4 h, float acc) {
    acc = dot2acc(u2h(u.x), u2h(h.x), acc);
    acc = dot2acc(u2h(u.y), u2h(h.y), acc);
    acc = dot2acc(u2h(u.z), u2h(h.z), acc);
    acc = dot2acc(u2h(u.w), u2h(h.w), acc);
    return acc;
}

__device__ __forceinline__ float fast_sigmoid(float x) {
    return 1.f / (1.f + __expf(-x));
}
__device__ __forceinline__ float fast_tanh(float x) {
    x = fminf(fmaxf(x, -15.f), 15.f);
    float e = __expf(2.f * x);
    return (e - 1.f) / (e + 1.f);
}

// ------------------------------------------------------------------
// K1: embedding gather -> f16, K zero-padded to K0PAD
// ------------------------------------------------------------------
__global__ void k_gather(const int* __restrict__ words,
                         const float* __restrict__ emb,
                         _Float16* __restrict__ X0h)
{
    int row = blockIdx.x;          // row = t*32 + b
    int t = row >> 5;
    int b = row & 31;
    int w = words[b * SEQ + t];
    const float* src = emb + (size_t)w * EDIM;
    _Float16* dst = X0h + (size_t)row * K0PAD;
    for (int e = threadIdx.x; e < K0PAD; e += blockDim.x)
        dst[e] = (e < EDIM) ? (_Float16)src[e] : (_Float16)0.f;
}

// ------------------------------------------------------------------
// K1c: cast W (N,K) f32 -> (N,Kpad) f16, zero-padded
// ------------------------------------------------------------------
__global__ void k_castW(const float* __restrict__ W,
                        _Float16* __restrict__ Wh,
                        int N, int K, int Kpad)
{
    int idx = blockIdx.x * blockDim.x + threadIdx.x;
    if (idx >= N * Kpad) return;
    int n = idx / Kpad, k = idx % Kpad;
    Wh[idx] = (k < K) ? (_Float16)W[(size_t)n * K + k] : (_Float16)0.f;
}

// ------------------------------------------------------------------
// K1b: pack Whh (2,800,200) f32 -> Upk fp16, chunk-major coalesced
// ------------------------------------------------------------------
__global__ void k_pack(const float* __restrict__ Whh,
                       _Float16* __restrict__ Upk)
{
    int idx = blockIdx.x * blockDim.x + threadIdx.x;   // (d*KC+kc)*800 + r
    if (idx >= 2 * KC * 800) return;
    int r  = idx % 800;
    int kc = (idx / 800) % KC;
    int d  = idx / (800 * KC);
    const float* src = Whh + ((size_t)d * G4 + r) * HDIM + kc * 8;
    _Float16* dst = Upk + (size_t)idx * 8;
#pragma unroll
    for (int j = 0; j < 8; ++j) dst[j] = (_Float16)src[j];
}

// ------------------------------------------------------------------
// K2/K4: MFMA f16 GEMM:  C[M,N] = A[M,Kpad] @ Bw[N,Kpad]^T + bias[N]
// (proven in R13: ~15-30 us each, correct)
// ------------------------------------------------------------------
#define GBM 64
#define GBN 64
#define GBK 32
#define GLD 40

__global__ __launch_bounds__(256)
void k_gemm_mfma(const _Float16* __restrict__ A,
                 const _Float16* __restrict__ Bw,
                 const float* __restrict__ bias,
                 float* __restrict__ C,
                 int M, int N, int Kpad)
{
    __shared__ __align__(16) _Float16 As[GBM][GLD];
    __shared__ __align__(16) _Float16 Bs[GBN][GLD];
    int tid = threadIdx.x;
    int wave = tid >> 6;
    int lane = tid & 63;
    int bm = blockIdx.y * GBM, bn = blockIdx.x * GBN;

    int srow = tid >> 2;          // staging: row 0..63
    int sseg = (tid & 3) * 8;     // k-segment 0,8,16,24

    f32x4 acc0 = {0,0,0,0}, acc1 = {0,0,0,0}, acc2 = {0,0,0,0}, acc3 = {0,0,0,0};
    int am = lane & 15;
    int kg = (lane >> 4) * 8;

    for (int k0 = 0; k0 < Kpad; k0 += GBK) {
        *(f16x8*)&As[srow][sseg] = *(const f16x8*)&A[(size_t)(bm + srow) * Kpad + k0 + sseg];
        *(f16x8*)&Bs[srow][sseg] = *(const f16x8*)&Bw[(size_t)(bn + srow) * Kpad + k0 + sseg];
        __syncthreads();
        f16x8 af = *(const f16x8*)&As[wave * 16 + am][kg];
        f16x8 b0 = *(const f16x8*)&Bs[ 0 + am][kg];
        f16x8 b1 = *(const f16x8*)&Bs[16 + am][kg];
        f16x8 b2 = *(const f16x8*)&Bs[32 + am][kg];
        f16x8 b3 = *(const f16x8*)&Bs[48 + am][kg];
        acc0 = __builtin_amdgcn_mfma_f32_16x16x32_f16(af, b0, acc0, 0, 0, 0);
        acc1 = __builtin_amdgcn_mfma_f32_16x16x32_f16(af, b1, acc1, 0, 0, 0);
        acc2 = __builtin_amdgcn_mfma_f32_16x16x32_f16(af, b2, acc2, 0, 0, 0);
        acc3 = __builtin_amdgcn_mfma_f32_16x16x32_f16(af, b3, acc3, 0, 0, 0);
        __syncthreads();
    }
    int col0 = lane & 15;
    int row0 = (lane >> 4) * 4;
#pragma unroll
    for (int r2 = 0; r2 < 4; ++r2) {
        int m = bm + wave * 16 + row0 + r2;
        float* crow = &C[(size_t)m * N + bn];
        crow[ 0 + col0] = acc0[r2] + bias[bn +  0 + col0];
        crow[16 + col0] = acc1[r2] + bias[bn + 16 + col0];
        crow[32 + col0] = acc2[r2] + bias[bn + 32 + col0];
        crow[48 + col0] = acc3[r2] + bias[bn + 48 + col0];
    }
}

// ------------------------------------------------------------------
// K3/K5: recurrent BiLSTM layer -- R6's proven structure (209 us):
// 832 threads / 13 waves (TLP saturates L2 stream at ~70 B/cyc),
// 1 gate-row per thread, 21 chunks streamed from L2 + 4 in static
// LDS (the refit-optimal split), g_lds exchange, 2 barriers/step.
// Added vs R6: f16 Houth side-output for the layer-1 MFMA GEMM.
// Known floor of this structure: LDS register-delivery (h-broadcasts)
// balanced against the L2 stream -- ~3900 cyc/step.
// ------------------------------------------------------------------
__global__ __launch_bounds__(832)
void k_lstm(const float* __restrict__ Xg,
            const _Float16* __restrict__ Upk,  // (2, KC, 800, 8) halves
            float* __restrict__ Hout,          // (S, B, 400) f32
            _Float16* __restrict__ Houth)      // (S*B, 416) f16
{
    int blk = blockIdx.x;      // 0..63
    int d = blk >> 5;          // direction
    int b = blk & 31;          // batch
    int r = threadIdx.x;       // gate row
    int rr = (r < G4) ? r : (G4 - 1);   // clamped

    __shared__ __align__(16) _Float16 hbuf[2][HDIM];
    __shared__ float g_lds[G4];
    __shared__ __align__(16) _Float16 lds_u[NLDS][800][8];  // 51.2 KB

    const _Float16* up_ptr = Upk + ((size_t)d * KC * 800 + rr) * 8;

    // LDS chunks NSTREAM..KC-1: each worker writes its own row
    if (r < G4) {
#pragma unroll
        for (int j = 0; j < NLDS; ++j)
            *(uint4*)&lds_u[j][r][0] =
                *(const uint4*)(up_ptr + (size_t)(NSTREAM + j) * CHSTRIDE);
    }

    if (r < HDIM) hbuf[0][r] = (_Float16)0.f;
    float c = 0.f;

    const float* xg_ptr = Xg + (size_t)b * NGATE + (size_t)d * G4 + rr;
    const ptrdiff_t sstride = (ptrdiff_t)BATCH * NGATE;

    __syncthreads();

    int tt0 = d ? (SEQ - 1) : 0;
    float xg_c = xg_ptr[(ptrdiff_t)tt0 * sstride];

    const _Float16* hcur = hbuf[0];
    _Float16* hnxt = hbuf[1];

#pragma unroll 1
    for (int t = 0; t < SEQ; ++t) {
        int tt = d ? (SEQ - 1 - t) : t;
        // prefetch next step's Xg element
        float xg_n = 0.f;
        if (t + 1 < SEQ)
            xg_n = xg_ptr[(ptrdiff_t)(d ? (SEQ - 2 - t) : (t + 1)) * sstride];

        float a0 = xg_c, a1 = 0.f;
        // streamed chunks 0..20 from L2 (coalesced across lanes; full
        // unroll -> many outstanding loads, 13-wave TLP hides latency)
#pragma unroll
        for (int kc = 0; kc < NSTREAM; ++kc) {
            uint4 uv = *(const uint4*)(up_ptr + (size_t)kc * CHSTRIDE);
            uint4 hv = *(const uint4*)&hcur[8 * kc];
            if (kc & 1) a1 = dot8(uv, hv, a1);
            else        a0 = dot8(uv, hv, a0);
        }
        // LDS-resident chunks 21..24
#pragma unroll
        for (int j = 0; j < NLDS; ++j) {
            uint4 uv = *(const uint4*)&lds_u[j][rr][0];
            uint4 hv = *(const uint4*)&hcur[8 * (NSTREAM + j)];
            if ((NSTREAM + j) & 1) a1 = dot8(uv, hv, a1);
            else                   a0 = dot8(uv, hv, a0);
        }
        if (r < G4) g_lds[r] = a0 + a1;
        __syncthreads();

        if (r < HDIM) {
            float gi = g_lds[r];
            float gf = g_lds[HDIM + r];
            float gg = g_lds[2 * HDIM + r];
            float go = g_lds[3 * HDIM + r];
            float si = fast_sigmoid(gi);
            float sf = fast_sigmoid(gf);
            float so = fast_sigmoid(go);
            c = sf * c + si * fast_tanh(gg);
            float hh = so * fast_tanh(c);
            hnxt[r] = (_Float16)hh;
            size_t rowi = (size_t)tt * BATCH + b;
            Hout[rowi * (2 * HDIM) + d * HDIM + r] = hh;
            Houth[rowi * K1PAD + d * HDIM + r] = (_Float16)hh;
        } else if (d == 0 && r >= 800 && r < 816) {
            // zero K-pad columns 400..415 (workspace is poisoned)
            Houth[((size_t)tt * BATCH + b) * K1PAD + 400 + (r - 800)] = (_Float16)0.f;
        }
        __syncthreads();

        const _Float16* tmp = hcur; hcur = hnxt; hnxt = (_Float16*)tmp;
        xg_c = xg_n;
    }
}

// ------------------------------------------------------------------
// K6: out[b][s][o] = sigmoid(H1[s][b][:] . Wo[o][:] + bo[o])
// ------------------------------------------------------------------
__global__ void k_out(const float* __restrict__ H1,
                      const float* __restrict__ Wo,
                      const float* __restrict__ bo,
                      float* __restrict__ out)
{
    int idx = blockIdx.x * blockDim.x + threadIdx.x;
    if (idx >= BATCH * SEQ * 17) return;
    int o = idx % 17;
    int bs = idx / 17;
    int b = bs >> 7;      // /128
    int s = bs & 127;
    const float* hrow = H1 + ((size_t)(s * BATCH + b)) * (2 * HDIM);
    const float* wrow = Wo + (size_t)o * (2 * HDIM);
    float acc = bo[o];
#pragma unroll 4
    for (int j = 0; j < 2 * HDIM; ++j) acc += hrow[j] * wrow[j];
    out[idx] = 1.f / (1.f + __expf(-acc));
}

// ------------------------------------------------------------------
extern "C" void kernel_launch(void* const* d_in, const int* in_sizes, int n_in,
                              void* d_out, int out_size, void* d_ws, size_t ws_size,
                              hipStream_t stream)
{
    const int*   words = (const int*)d_in[0];
    // d_in[1] chars, d_in[2] lens: dead code in the reference
    const float* emb   = (const float*)d_in[3];
    // d_in[4..6]: char conv params, dead
    const float* Wih0  = (const float*)d_in[7];
    const float* Whh0  = (const float*)d_in[8];
    const float* b0    = (const float*)d_in[9];
    const float* Wih1  = (const float*)d_in[10];
    const float* Whh1  = (const float*)d_in[11];
    const float* b1    = (const float*)d_in[12];
    const float* Wo    = (const float*)d_in[13];
    const float* bo    = (const float*)d_in[14];
    float* out = (float*)d_out;

    char* ws = (char*)d_ws;
    const size_t X0H_OFF = 0;                                   // 4096*320*2
    const size_t W0H_OFF = X0H_OFF + (size_t)4096 * K0PAD * 2;
    const size_t W1H_OFF = W0H_OFF + (size_t)NGATE * K0PAD * 2;
    const size_t UP0_OFF = W1H_OFF + (size_t)NGATE * K1PAD * 2;
    const size_t UP1_OFF = UP0_OFF + (size_t)2 * KC * 800 * 8 * 2;
    const size_t XG_OFF  = UP1_OFF + (size_t)2 * KC * 800 * 8 * 2;
    const size_t H1_OFF  = XG_OFF + (size_t)SEQ * BATCH * NGATE * 4;
    const size_t HT0_OFF = H1_OFF + (size_t)SEQ * BATCH * 2 * HDIM * 4;

    _Float16* X0h   = (_Float16*)(ws + X0H_OFF);
    _Float16* W0h   = (_Float16*)(ws + W0H_OFF);
    _Float16* W1h   = (_Float16*)(ws + W1H_OFF);
    _Float16* Upk0  = (_Float16*)(ws + UP0_OFF);
    _Float16* Upk1  = (_Float16*)(ws + UP1_OFF);
    float*    Xg    = (float*)(ws + XG_OFF);
    float*    H1    = (float*)(ws + H1_OFF);
    float*    Hdump = H1;                       // layer-0 f32 out (unused)
    _Float16* Houth0 = (_Float16*)(ws + HT0_OFF);
    _Float16* HouthD = Houth0;                  // layer-1 f16 out (unused)

    // 1. gather embeddings -> X0h f16 (4096, 320)
    k_gather<<<SEQ * BATCH, 128, 0, stream>>>(words, emb, X0h);

    // 1b. weight casts + recurrent packs
    int ncast0 = NGATE * K0PAD, ncast1 = NGATE * K1PAD;
    k_castW<<<(ncast0 + 255) / 256, 256, 0, stream>>>(Wih0, W0h, NGATE, EDIM, K0PAD);
    k_castW<<<(ncast1 + 255) / 256, 256, 0, stream>>>(Wih1, W1h, NGATE, 2 * HDIM, K1PAD);
    int npack = 2 * KC * 800;
    k_pack<<<(npack + 255) / 256, 256, 0, stream>>>(Whh0, Upk0);
    k_pack<<<(npack + 255) / 256, 256, 0, stream>>>(Whh1, Upk1);

    // 2. layer-0 input GEMM (MFMA): Xg = X0h @ W0h^T + b0
    dim3 ggrid(NGATE / GBN, (SEQ * BATCH) / GBM);
    k_gemm_mfma<<<ggrid, 256, 0, stream>>>(X0h, W0h, b0, Xg,
                                           SEQ * BATCH, NGATE, K0PAD);

    // 3. layer-0 recurrence -> Houth0 (f16) [+ f32 dump]
    k_lstm<<<64, 832, 0, stream>>>(Xg, Upk0, Hdump, Houth0);

    // 4. layer-1 input GEMM (MFMA): Xg = Houth0 @ W1h^T + b1
    k_gemm_mfma<<<ggrid, 256, 0, stream>>>(Houth0, W1h, b1, Xg,
                                           SEQ * BATCH, NGATE, K1PAD);

    // 5. layer-1 recurrence -> H1 (f32) [+ f16 dump]
    k_lstm<<<64, 832, 0, stream>>>(Xg, Upk1, H1, HouthD);

    // 6. output head
    int nout = BATCH * SEQ * 17;
    k_out<<<(nout + 255) / 256, 256, 0, stream>>>(H1, Wo, bo, out);
}